// Round 2
// baseline (1087.088 us; speedup 1.0000x reference)
//
#include <hip/hip_runtime.h>
#include <cstdint>
#include <cstddef>

// B=2, H=16, S=2048, D=64. fp32 inputs (Q,K,V), int mask (width auto-detected),
// fp32 outputs: [context (4.19M) | attn_prob (134.2M)] concatenated.
#define S_LEN 2048
#define D_HEAD 64
#define NBH 32

typedef __attribute__((ext_vector_type(8))) short short8;
typedef __attribute__((ext_vector_type(8))) unsigned short ushort8;
typedef __attribute__((ext_vector_type(4))) float floatx4;

__device__ __forceinline__ unsigned short f2bf(float f){
  union { float f; unsigned int i; } v; v.f = f;
  unsigned int u = v.i;
  u += 0x7fffu + ((u >> 16) & 1u);     // RNE
  return (unsigned short)(u >> 16);
}
__device__ __forceinline__ float bf2f(unsigned short u){
  union { unsigned int i; float f; } v; v.i = ((unsigned int)u) << 16; return v.f;
}

// XOR swizzle at 16B granularity: kills the 4KB-row-stride bank aliasing with no padding
// (P tile must stay exactly 64KB). offset in bf16 elements.
__device__ __forceinline__ int swz(int row, int col){
  return row * S_LEN + ((((col >> 3) ^ row) & 7) << 3) + ((col >> 3) & ~7) * 8 + (col & 7);
}

// ---- mask width detect: int32 0/1 -> every 4B word <= 1; uint8 0/1 -> words >1 whp.
__global__ void detect_mask_kernel(const unsigned int* __restrict__ m, int* __restrict__ flag){
  __shared__ int f;
  if (threadIdx.x == 0) f = 0;
  __syncthreads();
  if (m[threadIdx.x] > 1u) atomicOr(&f, 1);
  __syncthreads();
  if (threadIdx.x == 0) *flag = f;   // 0 = int32, 1 = uint8
}

// ---- K fp32 -> Kb bf16 (same layout). 8 elems/thread.
__global__ void convK_kernel(const float* __restrict__ K, unsigned short* __restrict__ Kb){
  const size_t i = ((size_t)blockIdx.x * 256 + threadIdx.x) * 8;
  floatx4 x0 = *(const floatx4*)(K + i);
  floatx4 x1 = *(const floatx4*)(K + i + 4);
  ushort8 o;
#pragma unroll
  for (int j = 0; j < 4; ++j){ o[j] = f2bf(x0[j]); o[4 + j] = f2bf(x1[j]); }
  *(ushort8*)(Kb + i) = o;
}

// ---- V fp32 -> Vt bf16 transposed: Vt[bh][n][k] (k contiguous for PV B-frags).
__global__ void vtrans_kernel(const float* __restrict__ V, unsigned short* __restrict__ Vt){
  const int bh = blockIdx.y;
  const int n  = threadIdx.x & 63;
  const int k0 = blockIdx.x * 32 + (threadIdx.x >> 6) * 8;
  const float* Vp = V + (size_t)bh * S_LEN * D_HEAD;
  ushort8 o;
#pragma unroll
  for (int i = 0; i < 8; ++i) o[i] = f2bf(Vp[(size_t)(k0 + i) * D_HEAD + n]);
  *(ushort8*)(Vt + (size_t)bh * D_HEAD * S_LEN + (size_t)n * S_LEN + k0) = o;
}

// ---- fused attention: per block = 16 q-rows x full S.
// Phase 1: QK^T (bf16 MFMA), mask, exp -> P tile (bf16, LDS, swizzled) + rowsum partials.
// Phase 2: cross-wave rowsum reduce via ws-global (LDS is 100% P tile). inv = 1/sum.
// Phase 3: PV from LDS A-frags + Vt B-frags; ctx = acc * inv (fp32 out).
// Phase 4: prob = P * inv (fp32 out), coalesced 256B stores.
// MFMA 16x16x32 bf16: A/B frag elem [m|n = lane&15][k = (lane>>4)*8 + j];
// C/D: col = lane&15, row = (lane>>4)*4 + reg.   (m89/m91-verified layouts)
__global__ __launch_bounds__(256) void attn_kernel(
    const float* __restrict__ Q, const unsigned short* __restrict__ Kb,
    const void* __restrict__ maskp, const int* __restrict__ flag,
    const unsigned short* __restrict__ Vt,
    float* __restrict__ prob, float* __restrict__ ctx,
    float* __restrict__ redg, float* __restrict__ invg){

  __shared__ unsigned short Pt[16 * S_LEN];   // exactly 64 KB

  const int bh   = blockIdx.y;
  const int qt   = blockIdx.x;
  const int q0g  = bh * S_LEN + qt * 16;      // row index into flattened [BH*S]
  const int tid  = threadIdx.x;
  const int wave = tid >> 6;
  const int lane = tid & 63;
  const int quad = lane >> 4;
  const int r16  = lane & 15;
  const int blk  = bh * gridDim.x + qt;

  // ---- Phase 1 ----
  const float* qrow = Q + (size_t)(q0g + r16) * D_HEAD + quad * 8;
  short8 a0, a1;
  {
    floatx4 x0 = *(const floatx4*)(qrow);
    floatx4 x1 = *(const floatx4*)(qrow + 4);
    floatx4 y0 = *(const floatx4*)(qrow + 32);
    floatx4 y1 = *(const floatx4*)(qrow + 36);
#pragma unroll
    for (int j = 0; j < 4; ++j){
      a0[j] = (short)f2bf(x0[j]); a0[4 + j] = (short)f2bf(x1[j]);
      a1[j] = (short)f2bf(y0[j]); a1[4 + j] = (short)f2bf(y1[j]);
    }
  }

  const bool mInt = (*flag) == 0;
  const unsigned int*  mI = (const unsigned int*)maskp;
  const unsigned char* mB = (const unsigned char*)maskp;

  float racc[4] = {0.f, 0.f, 0.f, 0.f};

  for (int t = 0; t < 32; ++t){
    const int s0 = wave * 512 + t * 16;
    const unsigned short* krow = Kb + (size_t)(bh * S_LEN + s0 + r16) * D_HEAD + quad * 8;
    const short8 b0 = *(const short8*)(krow);
    const short8 b1 = *(const short8*)(krow + 32);
    unsigned int mv[4];
    if (mInt){
#pragma unroll
      for (int i = 0; i < 4; ++i)
        mv[i] = mI[(size_t)(q0g + quad*4 + i) * S_LEN + s0 + r16];
    } else {
#pragma unroll
      for (int i = 0; i < 4; ++i)
        mv[i] = mB[(size_t)(q0g + quad*4 + i) * S_LEN + s0 + r16];
    }
    floatx4 c = {0.f, 0.f, 0.f, 0.f};
    c = __builtin_amdgcn_mfma_f32_16x16x32_bf16(a0, b0, c, 0, 0, 0);
    c = __builtin_amdgcn_mfma_f32_16x16x32_bf16(a1, b1, c, 0, 0, 0);
#pragma unroll
    for (int i = 0; i < 4; ++i){
      // masked -> -1e4 -> exp underflows to exactly 0 in the fp32 reference too
      const float p = mv[i] ? 0.0f : __expf(c[i] * 0.125f);
      racc[i] += p;
      Pt[swz(quad*4 + i, s0 + r16)] = f2bf(p);
    }
  }

  // ---- Phase 2: rowsums ----
#pragma unroll
  for (int off = 8; off; off >>= 1){
#pragma unroll
    for (int i = 0; i < 4; ++i) racc[i] += __shfl_xor(racc[i], off, 16);
  }
  if (r16 == 0){
#pragma unroll
    for (int i = 0; i < 4; ++i) redg[(size_t)blk * 64 + wave * 16 + quad*4 + i] = racc[i];
  }
  __syncthreads();   // P tile complete + partials visible
  if (tid < 16){
    float s = 0.f;
#pragma unroll
    for (int w = 0; w < 4; ++w) s += redg[(size_t)blk * 64 + w * 16 + tid];
    invg[(size_t)blk * 16 + tid] = (s > 0.f) ? (1.0f / s) : 0.0f;
  }
  __syncthreads();

  // ---- Phase 3: PV. wave w -> ctx cols [16w, 16w+16) ----
  float inv4[4];
#pragma unroll
  for (int i = 0; i < 4; ++i) inv4[i] = invg[(size_t)blk * 16 + quad*4 + i];

  const unsigned short* vrow = Vt + (size_t)bh * D_HEAD * S_LEN
                                  + (size_t)(wave * 16 + r16) * S_LEN + quad * 8;
  floatx4 c = {0.f, 0.f, 0.f, 0.f};
  for (int kk = 0; kk < 64; ++kk){
    const short8 b = *(const short8*)(vrow + kk * 32);
    const short8 a = *(const short8*)(&Pt[swz(r16, kk * 32 + quad * 8)]);
    c = __builtin_amdgcn_mfma_f32_16x16x32_bf16(a, b, c, 0, 0, 0);
  }
#pragma unroll
  for (int i = 0; i < 4; ++i)
    ctx[(size_t)(q0g + quad*4 + i) * D_HEAD + wave * 16 + r16] = c[i] * inv4[i];

  // ---- Phase 4: normalized prob (no barrier needed: Pt only read from here on) ----
#pragma unroll
  for (int rr = 0; rr < 4; ++rr){
    const int row = wave * 4 + rr;
    const float iv = invg[(size_t)blk * 16 + row];
    float* pg = prob + (size_t)(q0g + row) * S_LEN;
    for (int j = 0; j < 32; ++j){
      const int col = j * 64 + lane;
      pg[col] = bf2f(Pt[swz(row, col)]) * iv;
    }
  }
}

extern "C" void kernel_launch(void* const* d_in, const int* in_sizes, int n_in,
                              void* d_out, int out_size, void* d_ws, size_t ws_size,
                              hipStream_t stream) {
  const float* Q = (const float*)d_in[0];
  const float* K = (const float*)d_in[1];
  const float* V = (const float*)d_in[2];
  const void*  M = d_in[3];

  float* ctx  = (float*)d_out;
  float* prob = (float*)d_out + (size_t)NBH * S_LEN * D_HEAD;

  // ws: [0,4) flag | [4KB, +1MB) redg | [+1MB, +256KB) invg | [2MB,10MB) Kb | [10MB,18MB) Vt
  int*   flag = (int*)d_ws;
  float* redg = (float*)((char*)d_ws + (1u << 12));
  float* invg = (float*)((char*)d_ws + (1u << 12) + (1u << 20));
  unsigned short* Kb = (unsigned short*)((char*)d_ws + (2u << 20));
  unsigned short* Vt = (unsigned short*)((char*)d_ws + (10u << 20));

  hipLaunchKernelGGL(detect_mask_kernel, dim3(1), dim3(256), 0, stream,
                     (const unsigned int*)M, flag);
  hipLaunchKernelGGL(convK_kernel, dim3(2048), dim3(256), 0, stream, K, Kb);
  hipLaunchKernelGGL(vtrans_kernel, dim3(S_LEN/32, NBH), dim3(256), 0, stream, V, Vt);
  hipLaunchKernelGGL(attn_kernel, dim3(S_LEN/16, NBH), dim3(256), 0, stream,
                     Q, Kb, M, flag, Vt, prob, ctx, redg, invg);
}